// Round 3
// baseline (386.488 us; speedup 1.0000x reference)
//
#include <hip/hip_runtime.h>
#include <hip/hip_cooperative_groups.h>

namespace cg = cooperative_groups;

// Problem constants
#define NB 2
#define CC 512
#define NN 2304
#define NH 8
#define DD 16
#define TT 128          // NH*DD
#define O3 384          // 3*TT

typedef __attribute__((ext_vector_type(4))) float f32x4;
typedef __attribute__((ext_vector_type(8))) __bf16 bf16x8;
typedef __attribute__((ext_vector_type(4))) __bf16 bf16x4;
typedef __attribute__((ext_vector_type(4))) _Float16 f16x4;

// workspace layout (bytes)
#define OFF_XT 0u               // 2*2304*512*2 = 4,718,592
#define OFF_WQ 4718592u         // 384*512*2    =   393,216
#define OFF_WO 5111808u         // 512*128*2    =   131,072
#define OFF_Q  5242880u         // 2*8*2304*16*2 = 1,179,648
#define OFF_K  6422528u
#define OFF_VT 7602176u
#define OFF_AO 8781824u         // 2*2304*128*2 = 1,179,648 -> 9,961,472

// ===========================================================================
// Cooperative mega-kernel. Every stage is a grid-stride loop -> correct for
// ANY grid size; grid is sized at launch from the occupancy query so the
// cooperative-launch validation cannot reject it (R2 failed with an
// unchecked hipErrorCooperativeLaunchTooLarge -> output stayed zero).
// launch_bounds(256,2): 256 VGPR budget, no spills, >=2 blocks/CU.
// ===========================================================================
__global__ __launch_bounds__(256, 2) void mega(
    const float* __restrict__ x, const float* __restrict__ wqkv,
    const float* __restrict__ temp, const float* __restrict__ wout,
    const float* __restrict__ gamma, const float* __restrict__ beta,
    float* __restrict__ out, char* __restrict__ ws)
{
    __bf16*   xT  = (__bf16*)(ws + OFF_XT);
    __bf16*   wqb = (__bf16*)(ws + OFF_WQ);
    __bf16*   wob = (__bf16*)(ws + OFF_WO);
    _Float16* Q   = (_Float16*)(ws + OFF_Q);
    _Float16* K   = (_Float16*)(ws + OFF_K);
    _Float16* VT  = (_Float16*)(ws + OFF_VT);
    __bf16*   AO  = (__bf16*)(ws + OFF_AO);

    __shared__ union {
        float tile[64][65];                                 // stage A
        struct { float O[4][16][64]; float L[4][64]; } c;   // stage C (17.4 KB)
        struct { float rs[4]; float rq[4]; } e;             // stage E
    } sm;

    cg::grid_group grid = cg::this_grid();
    const int gsz = gridDim.x;
    const int bid = blockIdx.x;
    const int t = threadIdx.x;
    const int lane = t & 63, wave = t >> 6;
    const int quad = lane >> 4, col = lane & 15;

    // ---------------- Stage A: x [b,c,n] f32 -> xT [b,n,c] bf16 + w->bf16 ----
    for (int u = bid; u < 640; u += gsz) {
        if (u < 576) {
            int b = u / 288, rem = u % 288;
            int nt = rem / 8, cb = rem % 8;
            int n0 = nt * 64, c0 = cb * 64;
            int tc = t >> 6, tn = t & 63;
#pragma unroll
            for (int i = 0; i < 16; i++) {
                int cl = i * 4 + tc;
                sm.tile[cl][tn] = x[(size_t)(b * CC + c0 + cl) * NN + n0 + tn];
            }
            __syncthreads();
#pragma unroll
            for (int i = 0; i < 16; i++) {
                int nl = i * 4 + tc;
                xT[(size_t)(b * NN + n0 + nl) * CC + c0 + tn] = (__bf16)sm.tile[tn][nl];
            }
        } else {
            int wid = u - 576;
            int base = wid * 256 + t;
#pragma unroll
            for (int i = 0; i < 16; i++) {
                int j = base + i * 16384;         // covers 262144 = 384*512 + 512*128
                if (j < O3 * CC) wqb[j] = (__bf16)wqkv[j];
                else             wob[j - O3 * CC] = (__bf16)wout[j - O3 * CC];
            }
        }
        __syncthreads();   // tile reuse across grid-stride iterations
    }
    grid.sync();

    // ---------------- Stage B: QKV GEMM + fused L2 norm ----------------------
    for (int u = bid; u < 864; u += gsz) {
        int ob = u % 12, nt = (u / 12) % 36, b = u / 432;
        int n0 = nt * 64 + wave * 16;
        int o0 = ob * 32;

        f32x4 acc0 = {0.f, 0.f, 0.f, 0.f};
        f32x4 acc1 = {0.f, 0.f, 0.f, 0.f};

        const __bf16* arow  = xT + (size_t)(b * NN + n0 + col) * CC + quad * 8;
        const __bf16* brow0 = wqb + (size_t)(o0 + col) * CC + quad * 8;
        const __bf16* brow1 = brow0 + 16 * CC;

        bf16x8 a  = *(const bf16x8*)(arow);
        bf16x8 w0 = *(const bf16x8*)(brow0);
        bf16x8 w1 = *(const bf16x8*)(brow1);
#pragma unroll
        for (int ks = 0; ks < 16; ks++) {
            bf16x8 an, wn0, wn1;
            if (ks < 15) {
                an  = *(const bf16x8*)(arow + (ks + 1) * 32);
                wn0 = *(const bf16x8*)(brow0 + (ks + 1) * 32);
                wn1 = *(const bf16x8*)(brow1 + (ks + 1) * 32);
            }
            acc0 = __builtin_amdgcn_mfma_f32_16x16x32_bf16(a, w0, acc0, 0, 0, 0);
            acc1 = __builtin_amdgcn_mfma_f32_16x16x32_bf16(a, w1, acc1, 0, 0, 0);
            a = an; w0 = wn0; w1 = wn1;
        }

#pragma unroll
        for (int s = 0; s < 2; s++) {
            int oc = o0 + s * 16 + col;
            int d = oc & 15, h = (oc >> 4) & 7, kind = oc >> 7;  // 0=q 1=k 2=v
            f32x4 v = (s == 0) ? acc0 : acc1;
            if (kind < 2) {
                float ss0 = v[0] * v[0], ss1 = v[1] * v[1], ss2 = v[2] * v[2], ss3 = v[3] * v[3];
#pragma unroll
                for (int m = 1; m < 16; m <<= 1) {
                    ss0 += __shfl_xor(ss0, m);
                    ss1 += __shfl_xor(ss1, m);
                    ss2 += __shfl_xor(ss2, m);
                    ss3 += __shfl_xor(ss3, m);
                }
                v[0] *= 1.0f / fmaxf(sqrtf(ss0), 1e-12f);
                v[1] *= 1.0f / fmaxf(sqrtf(ss1), 1e-12f);
                v[2] *= 1.0f / fmaxf(sqrtf(ss2), 1e-12f);
                v[3] *= 1.0f / fmaxf(sqrtf(ss3), 1e-12f);
                _Float16* dst = (kind == 0 ? Q : K) + (size_t)(b * NH + h) * NN * DD;
#pragma unroll
                for (int r = 0; r < 4; r++) {
                    int n = n0 + quad * 4 + r;
                    dst[(size_t)n * DD + d] = (_Float16)v[r];
                }
            } else {
                f16x4 pk;
#pragma unroll
                for (int r = 0; r < 4; r++) pk[r] = (_Float16)v[r];
                int n = n0 + quad * 4;
                *(f16x4*)(VT + (size_t)((b * NH + h) * DD + d) * NN + n) = pk;
            }
        }
    }
    grid.sync();

    // ---------------- Stage C: attention (4 waves x 576 keys, LDS combine) ---
    for (int u = bid; u < 576; u += gsz) {
        int qt = u % 36, bh = u / 36;
        int kbase = wave * 576;               // 4 waves x 576 keys = 2304
        int qbase = qt * 64;

        const _Float16* Qb = Q + (size_t)bh * NN * DD;
        float tl2 = temp[bh & 7] * 1.4426950408889634f;

        f16x4 qf0 = *(const f16x4*)(Qb + (size_t)(qbase +  0 + col) * DD + quad * 4);
        f16x4 qf1 = *(const f16x4*)(Qb + (size_t)(qbase + 16 + col) * DD + quad * 4);
        f16x4 qf2 = *(const f16x4*)(Qb + (size_t)(qbase + 32 + col) * DD + quad * 4);
        f16x4 qf3 = *(const f16x4*)(Qb + (size_t)(qbase + 48 + col) * DD + quad * 4);

        f32x4 oa0 = {0.f,0.f,0.f,0.f}, oa1 = {0.f,0.f,0.f,0.f};
        f32x4 oa2 = {0.f,0.f,0.f,0.f}, oa3 = {0.f,0.f,0.f,0.f};
        float la0 = 0.f, la1 = 0.f, la2 = 0.f, la3 = 0.f;
        const f32x4 zc = {0.f,0.f,0.f,0.f};

        const _Float16* kp = K + (size_t)bh * NN * DD + (size_t)(kbase + col) * DD + quad * 4;
        const _Float16* vp = VT + (size_t)bh * DD * NN + (size_t)col * NN + kbase + quad * 4;

        f16x4 kfa = *(const f16x4*)(kp);
        f16x4 kfb = *(const f16x4*)(kp + 16 * DD);
        f16x4 vfa = *(const f16x4*)(vp);
        f16x4 vfb = *(const f16x4*)(vp + 16);

#define K2_CHUNK(KF, VF)                                                        \
    {                                                                           \
        f32x4 s0 = __builtin_amdgcn_mfma_f32_16x16x16f16(KF, qf0, zc, 0, 0, 0); \
        f32x4 s1 = __builtin_amdgcn_mfma_f32_16x16x16f16(KF, qf1, zc, 0, 0, 0); \
        f32x4 s2 = __builtin_amdgcn_mfma_f32_16x16x16f16(KF, qf2, zc, 0, 0, 0); \
        f32x4 s3 = __builtin_amdgcn_mfma_f32_16x16x16f16(KF, qf3, zc, 0, 0, 0); \
        f16x4 p0, p1, p2, p3;                                                   \
        _Pragma("unroll")                                                       \
        for (int r = 0; r < 4; ++r) {                                           \
            float e0 = __builtin_amdgcn_exp2f(tl2 * s0[r]);                     \
            float e1 = __builtin_amdgcn_exp2f(tl2 * s1[r]);                     \
            float e2 = __builtin_amdgcn_exp2f(tl2 * s2[r]);                     \
            float e3 = __builtin_amdgcn_exp2f(tl2 * s3[r]);                     \
            p0[r] = (_Float16)e0; la0 += e0;                                    \
            p1[r] = (_Float16)e1; la1 += e1;                                    \
            p2[r] = (_Float16)e2; la2 += e2;                                    \
            p3[r] = (_Float16)e3; la3 += e3;                                    \
        }                                                                       \
        oa0 = __builtin_amdgcn_mfma_f32_16x16x16f16(VF, p0, oa0, 0, 0, 0);      \
        oa1 = __builtin_amdgcn_mfma_f32_16x16x16f16(VF, p1, oa1, 0, 0, 0);      \
        oa2 = __builtin_amdgcn_mfma_f32_16x16x16f16(VF, p2, oa2, 0, 0, 0);      \
        oa3 = __builtin_amdgcn_mfma_f32_16x16x16f16(VF, p3, oa3, 0, 0, 0);      \
    }

        for (int g = 0; g < 18; ++g) {        // 18 groups x 32 keys = 576
            f16x4 kna, knb, vna, vnb;
            if (g < 17) {
                kna = *(const f16x4*)(kp + 32 * DD);
                knb = *(const f16x4*)(kp + 48 * DD);
                vna = *(const f16x4*)(vp + 32);
                vnb = *(const f16x4*)(vp + 48);
            }
            K2_CHUNK(kfa, vfa)
            K2_CHUNK(kfb, vfb)
            kfa = kna; kfb = knb; vfa = vna; vfb = vnb;
            kp += 32 * DD; vp += 32;
        }
#undef K2_CHUNK

        la0 += __shfl_xor(la0, 16); la0 += __shfl_xor(la0, 32);
        la1 += __shfl_xor(la1, 16); la1 += __shfl_xor(la1, 32);
        la2 += __shfl_xor(la2, 16); la2 += __shfl_xor(la2, 32);
        la3 += __shfl_xor(la3, 16); la3 += __shfl_xor(la3, 32);

#pragma unroll
        for (int r = 0; r < 4; ++r) {
            sm.c.O[wave][quad * 4 + r][ 0 + col] = oa0[r];
            sm.c.O[wave][quad * 4 + r][16 + col] = oa1[r];
            sm.c.O[wave][quad * 4 + r][32 + col] = oa2[r];
            sm.c.O[wave][quad * 4 + r][48 + col] = oa3[r];
        }
        float lv = (quad == 0) ? la0 : (quad == 1) ? la1 : (quad == 2) ? la2 : la3;
        sm.c.L[wave][quad * 16 + col] = lv;
        __syncthreads();

        // combine 4 key-split partials, write AO directly
        int q = t & 63, dg = t >> 6;          // dg 0..3 -> d = dg*4 .. +3
        float l = 0.f;
#pragma unroll
        for (int w = 0; w < 4; ++w) l += sm.c.L[w][q];
        float inv = 1.0f / l;
        float o0 = 0.f, o1 = 0.f, o2 = 0.f, o3 = 0.f;
#pragma unroll
        for (int w = 0; w < 4; ++w) {
            o0 += sm.c.O[w][dg * 4 + 0][q];
            o1 += sm.c.O[w][dg * 4 + 1][q];
            o2 += sm.c.O[w][dg * 4 + 2][q];
            o3 += sm.c.O[w][dg * 4 + 3][q];
        }
        int b = bh >> 3, h = bh & 7;
        bf16x4 pkv;
        pkv[0] = (__bf16)(o0 * inv);
        pkv[1] = (__bf16)(o1 * inv);
        pkv[2] = (__bf16)(o2 * inv);
        pkv[3] = (__bf16)(o3 * inv);
        *(bf16x4*)(AO + (size_t)(b * NN + qbase + q) * TT + h * DD + dg * 4) = pkv;
        __syncthreads();   // LDS reuse across grid-stride iterations
    }
    grid.sync();

    // ---------------- Stage D: projection (pre-BN f32 into out) --------------
    for (int u = bid; u < 1152; u += gsz) {
        int cb = u % 16, nt = (u / 16) % 36, b = u / 576;
        int n0 = nt * 64 + wave * 16, c0 = cb * 32;

        f32x4 acc0 = {0.f, 0.f, 0.f, 0.f};
        f32x4 acc1 = {0.f, 0.f, 0.f, 0.f};

        const __bf16* ab  = AO + (size_t)(b * NN + n0 + col) * TT + quad * 8;
        const __bf16* wb0 = wob + (size_t)(c0 + col) * TT + quad * 8;
        const __bf16* wb1 = wb0 + 16 * TT;
#pragma unroll
        for (int ks = 0; ks < 4; ks++) {
            bf16x8 a  = *(const bf16x8*)(ab + ks * 32);
            bf16x8 w0 = *(const bf16x8*)(wb0 + ks * 32);
            bf16x8 w1 = *(const bf16x8*)(wb1 + ks * 32);
            acc0 = __builtin_amdgcn_mfma_f32_16x16x32_bf16(a, w0, acc0, 0, 0, 0);
            acc1 = __builtin_amdgcn_mfma_f32_16x16x32_bf16(a, w1, acc1, 0, 0, 0);
        }
#pragma unroll
        for (int s = 0; s < 2; s++) {
            int c = c0 + s * 16 + col;
            float* dst = out + (size_t)(b * CC + c) * NN + n0 + quad * 4;
            *(f32x4*)dst = (s == 0) ? acc0 : acc1;
        }
    }
    grid.sync();

    // ---------------- Stage E: BatchNorm, unit = one channel (both batches) --
    for (int u = bid; u < 512; u += gsz) {
        int c = u;
        float vals[18];
        float s = 0.f, q = 0.f;
#pragma unroll
        for (int i = 0; i < 18; i++) {
            int j = i * 256 + t;          // 0..4607 over (b,n)
            int b = j / NN, n = j % NN;
            float v = out[(size_t)(b * CC + c) * NN + n];
            vals[i] = v; s += v; q += v * v;
        }
#pragma unroll
        for (int m = 1; m < 64; m <<= 1) { s += __shfl_xor(s, m); q += __shfl_xor(q, m); }
        if (lane == 0) { sm.e.rs[wave] = s; sm.e.rq[wave] = q; }
        __syncthreads();
        s = sm.e.rs[0] + sm.e.rs[1] + sm.e.rs[2] + sm.e.rs[3];
        q = sm.e.rq[0] + sm.e.rq[1] + sm.e.rq[2] + sm.e.rq[3];
        float mean = s * (1.0f / 4608.0f);
        float var  = q * (1.0f / 4608.0f) - mean * mean;
        float sc = rsqrtf(var + 1e-5f) * gamma[c];
        float sh = beta[c] - mean * sc;
#pragma unroll
        for (int i = 0; i < 18; i++) {
            int j = i * 256 + t;
            int b = j / NN, n = j % NN;
            out[(size_t)(b * CC + c) * NN + n] = vals[i] * sc + sh;
        }
        __syncthreads();   // rs/rq reuse across grid-stride iterations
    }
}

// ===========================================================================
// Fallback path: the round-1 verified 5-kernel pipeline (138.2 us), used if
// the cooperative launch is rejected.
// ===========================================================================
__global__ __launch_bounds__(256) void k0_convert(
    const float* __restrict__ x, const float* __restrict__ wqkv,
    const float* __restrict__ wout,
    __bf16* __restrict__ xT, __bf16* __restrict__ wqb, __bf16* __restrict__ wob)
{
    int bid = blockIdx.x;
    int t = threadIdx.x;
    if (bid < 576) {
        __shared__ float tile[64][65];
        int b = bid / 288, rem = bid % 288;
        int nt = rem / 8, cb = rem % 8;
        int n0 = nt * 64, c0 = cb * 64;
        int tc = t >> 6, tn = t & 63;
#pragma unroll
        for (int i = 0; i < 16; i++) {
            int cl = i * 4 + tc;
            tile[cl][tn] = x[(size_t)(b * CC + c0 + cl) * NN + n0 + tn];
        }
        __syncthreads();
#pragma unroll
        for (int i = 0; i < 16; i++) {
            int nl = i * 4 + tc;
            xT[(size_t)(b * NN + n0 + nl) * CC + c0 + tn] = (__bf16)tile[tn][nl];
        }
    } else {
        int wid = bid - 576;
        int base = wid * 256 + t;
#pragma unroll
        for (int i = 0; i < 16; i++) {
            int j = base + i * 16384;
            if (j < O3 * CC) wqb[j] = (__bf16)wqkv[j];
            else             wob[j - O3 * CC] = (__bf16)wout[j - O3 * CC];
        }
    }
}

__global__ __launch_bounds__(256) void k1_qkv(
    const __bf16* __restrict__ xT, const __bf16* __restrict__ wqb,
    _Float16* __restrict__ Q, _Float16* __restrict__ K, _Float16* __restrict__ VT)
{
    int ob = blockIdx.x, nt = blockIdx.y, b = blockIdx.z;
    int lane = threadIdx.x & 63, wave = threadIdx.x >> 6;
    int quad = lane >> 4, col = lane & 15;
    int n0 = nt * 64 + wave * 16;
    int o0 = ob * 32;

    f32x4 acc[2];
    acc[0] = (f32x4){0.f, 0.f, 0.f, 0.f};
    acc[1] = (f32x4){0.f, 0.f, 0.f, 0.f};

    const __bf16* arow = xT + (size_t)(b * NN + n0 + col) * CC + quad * 8;
    const __bf16* brow0 = wqb + (size_t)(o0 + col) * CC + quad * 8;
    const __bf16* brow1 = brow0 + 16 * CC;

    bf16x8 a  = *(const bf16x8*)(arow);
    bf16x8 w0 = *(const bf16x8*)(brow0);
    bf16x8 w1 = *(const bf16x8*)(brow1);
#pragma unroll
    for (int ks = 0; ks < 16; ks++) {
        bf16x8 an, wn0, wn1;
        if (ks < 15) {
            an  = *(const bf16x8*)(arow + (ks + 1) * 32);
            wn0 = *(const bf16x8*)(brow0 + (ks + 1) * 32);
            wn1 = *(const bf16x8*)(brow1 + (ks + 1) * 32);
        }
        acc[0] = __builtin_amdgcn_mfma_f32_16x16x32_bf16(a, w0, acc[0], 0, 0, 0);
        acc[1] = __builtin_amdgcn_mfma_f32_16x16x32_bf16(a, w1, acc[1], 0, 0, 0);
        a = an; w0 = wn0; w1 = wn1;
    }

#pragma unroll
    for (int s = 0; s < 2; s++) {
        int oc = o0 + s * 16 + col;
        int d = oc & 15, h = (oc >> 4) & 7, kind = oc >> 7;
        f32x4 v = acc[s];
        if (kind < 2) {
            float ss0 = v[0] * v[0], ss1 = v[1] * v[1], ss2 = v[2] * v[2], ss3 = v[3] * v[3];
#pragma unroll
            for (int m = 1; m < 16; m <<= 1) {
                ss0 += __shfl_xor(ss0, m);
                ss1 += __shfl_xor(ss1, m);
                ss2 += __shfl_xor(ss2, m);
                ss3 += __shfl_xor(ss3, m);
            }
            v[0] *= 1.0f / fmaxf(sqrtf(ss0), 1e-12f);
            v[1] *= 1.0f / fmaxf(sqrtf(ss1), 1e-12f);
            v[2] *= 1.0f / fmaxf(sqrtf(ss2), 1e-12f);
            v[3] *= 1.0f / fmaxf(sqrtf(ss3), 1e-12f);
            _Float16* dst = (kind == 0 ? Q : K) + (size_t)(b * NH + h) * NN * DD;
#pragma unroll
            for (int r = 0; r < 4; r++) {
                int n = n0 + quad * 4 + r;
                dst[(size_t)n * DD + d] = (_Float16)v[r];
            }
        } else {
            f16x4 pk;
#pragma unroll
            for (int r = 0; r < 4; r++) pk[r] = (_Float16)v[r];
            int n = n0 + quad * 4;
            *(f16x4*)(VT + (size_t)((b * NH + h) * DD + d) * NN + n) = pk;
        }
    }
}

__global__ __launch_bounds__(512) void k2_attn(
    const _Float16* __restrict__ Q, const _Float16* __restrict__ K,
    const _Float16* __restrict__ VT, const float* __restrict__ temp,
    __bf16* __restrict__ AO)
{
    __shared__ float Osh[8][16][64];
    __shared__ float Lsh[8][64];

    int qt = blockIdx.x, bh = blockIdx.y;
    int lane = threadIdx.x & 63, wave = threadIdx.x >> 6;
    int quad = lane >> 4, col = lane & 15;
    int kbase = wave * 288;
    int qbase = qt * 64;

    const _Float16* Qb = Q + (size_t)bh * NN * DD;
    float tl2 = temp[bh & 7] * 1.4426950408889634f;

    f16x4 qf0 = *(const f16x4*)(Qb + (size_t)(qbase +  0 + col) * DD + quad * 4);
    f16x4 qf1 = *(const f16x4*)(Qb + (size_t)(qbase + 16 + col) * DD + quad * 4);
    f16x4 qf2 = *(const f16x4*)(Qb + (size_t)(qbase + 32 + col) * DD + quad * 4);
    f16x4 qf3 = *(const f16x4*)(Qb + (size_t)(qbase + 48 + col) * DD + quad * 4);

    f32x4 oa0 = {0.f,0.f,0.f,0.f}, oa1 = {0.f,0.f,0.f,0.f};
    f32x4 oa2 = {0.f,0.f,0.f,0.f}, oa3 = {0.f,0.f,0.f,0.f};
    float la0 = 0.f, la1 = 0.f, la2 = 0.f, la3 = 0.f;
    const f32x4 zc = {0.f,0.f,0.f,0.f};

    const _Float16* kp = K + (size_t)bh * NN * DD + (size_t)(kbase + col) * DD + quad * 4;
    const _Float16* vp = VT + (size_t)bh * DD * NN + (size_t)col * NN + kbase + quad * 4;

    f16x4 kfa = *(const f16x4*)(kp);
    f16x4 kfb = *(const f16x4*)(kp + 16 * DD);
    f16x4 vfa = *(const f16x4*)(vp);
    f16x4 vfb = *(const f16x4*)(vp + 16);

#define K2_CHUNK(KF, VF)                                                        \
    {                                                                           \
        f32x4 s0 = __builtin_amdgcn_mfma_f32_16x16x16f16(KF, qf0, zc, 0, 0, 0); \
        f32x4 s1 = __builtin_amdgcn_mfma_f32_16x16x16f16(KF, qf1, zc, 0, 0, 0); \
        f32x4 s2 = __builtin_amdgcn_mfma_f32_16x16x16f16(KF, qf2, zc, 0, 0, 0); \
        f32x4 s3 = __builtin_amdgcn_mfma_f32_16x16x16f16(KF, qf3, zc, 0, 0, 0); \
        f16x4 p0, p1, p2, p3;                                                   \
        _Pragma("unroll")                                                       \
        for (int r = 0; r < 4; ++r) {                                           \
            float e0 = __builtin_amdgcn_exp2f(tl2 * s0[r]);                     \
            float e1 = __builtin_amdgcn_exp2f(tl2 * s1[r]);                     \
            float e2 = __builtin_amdgcn_exp2f(tl2 * s2[r]);                     \
            float e3 = __builtin_amdgcn_exp2f(tl2 * s3[r]);                     \
            p0[r] = (_Float16)e0; la0 += e0;                                    \
            p1[r] = (_Float16)e1; la1 += e1;                                    \
            p2[r] = (_Float16)e2; la2 += e2;                                    \
            p3[r] = (_Float16)e3; la3 += e3;                                    \
        }                                                                       \
        oa0 = __builtin_amdgcn_mfma_f32_16x16x16f16(VF, p0, oa0, 0, 0, 0);      \
        oa1 = __builtin_amdgcn_mfma_f32_16x16x16f16(VF, p1, oa1, 0, 0, 0);      \
        oa2 = __builtin_amdgcn_mfma_f32_16x16x16f16(VF, p2, oa2, 0, 0, 0);      \
        oa3 = __builtin_amdgcn_mfma_f32_16x16x16f16(VF, p3, oa3, 0, 0, 0);      \
    }

    for (int g = 0; g < 9; ++g) {
        f16x4 kna, knb, vna, vnb;
        if (g < 8) {
            kna = *(const f16x4*)(kp + 32 * DD);
            knb = *(const f16x4*)(kp + 48 * DD);
            vna = *(const f16x4*)(vp + 32);
            vnb = *(const f16x4*)(vp + 48);
        }
        K2_CHUNK(kfa, vfa)
        K2_CHUNK(kfb, vfb)
        kfa = kna; kfb = knb; vfa = vna; vfb = vnb;
        kp += 32 * DD; vp += 32;
    }
#undef K2_CHUNK

    la0 += __shfl_xor(la0, 16); la0 += __shfl_xor(la0, 32);
    la1 += __shfl_xor(la1, 16); la1 += __shfl_xor(la1, 32);
    la2 += __shfl_xor(la2, 16); la2 += __shfl_xor(la2, 32);
    la3 += __shfl_xor(la3, 16); la3 += __shfl_xor(la3, 32);

#pragma unroll
    for (int r = 0; r < 4; ++r) {
        Osh[wave][quad * 4 + r][ 0 + col] = oa0[r];
        Osh[wave][quad * 4 + r][16 + col] = oa1[r];
        Osh[wave][quad * 4 + r][32 + col] = oa2[r];
        Osh[wave][quad * 4 + r][48 + col] = oa3[r];
    }
    float lv = (quad == 0) ? la0 : (quad == 1) ? la1 : (quad == 2) ? la2 : la3;
    Lsh[wave][quad * 16 + col] = lv;
    __syncthreads();

    int t = threadIdx.x;
    int q = t & 63, dg = t >> 6;
    float l = 0.f;
#pragma unroll
    for (int w = 0; w < 8; ++w) l += Lsh[w][q];
    float inv = 1.0f / l;
    float o0 = 0.f, o1 = 0.f;
#pragma unroll
    for (int w = 0; w < 8; ++w) {
        o0 += Osh[w][dg * 2 + 0][q];
        o1 += Osh[w][dg * 2 + 1][q];
    }
    int b = bh >> 3, h = bh & 7;
    __bf16* dst = AO + (size_t)(b * NN + qbase + q) * TT + h * DD + dg * 2;
    dst[0] = (__bf16)(o0 * inv);
    dst[1] = (__bf16)(o1 * inv);
}

__global__ __launch_bounds__(256) void k3_proj(
    const __bf16* __restrict__ AO, const __bf16* __restrict__ wob,
    float* __restrict__ out)
{
    int cb = blockIdx.x, nt = blockIdx.y, b = blockIdx.z;
    int lane = threadIdx.x & 63, wave = threadIdx.x >> 6;
    int quad = lane >> 4, col = lane & 15;
    int n0 = nt * 64 + wave * 16, c0 = cb * 32;

    f32x4 acc[2];
    acc[0] = (f32x4){0.f, 0.f, 0.f, 0.f};
    acc[1] = (f32x4){0.f, 0.f, 0.f, 0.f};

    const __bf16* ab = AO + (size_t)(b * NN + n0 + col) * TT + quad * 8;
    const __bf16* wb0 = wob + (size_t)(c0 + col) * TT + quad * 8;
    const __bf16* wb1 = wb0 + 16 * TT;
#pragma unroll
    for (int ks = 0; ks < 4; ks++) {
        bf16x8 a  = *(const bf16x8*)(ab + ks * 32);
        bf16x8 w0 = *(const bf16x8*)(wb0 + ks * 32);
        bf16x8 w1 = *(const bf16x8*)(wb1 + ks * 32);
        acc[0] = __builtin_amdgcn_mfma_f32_16x16x32_bf16(a, w0, acc[0], 0, 0, 0);
        acc[1] = __builtin_amdgcn_mfma_f32_16x16x32_bf16(a, w1, acc[1], 0, 0, 0);
    }
#pragma unroll
    for (int s = 0; s < 2; s++) {
        int c = c0 + s * 16 + col;
        float* dst = out + (size_t)(b * CC + c) * NN + n0 + quad * 4;
        *(f32x4*)dst = acc[s];
    }
}

__global__ __launch_bounds__(256) void k4_bn(
    float* __restrict__ out, const float* __restrict__ gamma,
    const float* __restrict__ beta)
{
    int c = blockIdx.x;
    int t = threadIdx.x;
    float vals[18];
    float s = 0.f, q = 0.f;
#pragma unroll
    for (int i = 0; i < 18; i++) {
        int j = i * 256 + t;
        int b = j / NN, n = j % NN;
        float v = out[(size_t)(b * CC + c) * NN + n];
        vals[i] = v; s += v; q += v * v;
    }
#pragma unroll
    for (int m = 1; m < 64; m <<= 1) { s += __shfl_xor(s, m); q += __shfl_xor(q, m); }
    __shared__ float rs[4], rq[4];
    int lane = t & 63, wave = t >> 6;
    if (lane == 0) { rs[wave] = s; rq[wave] = q; }
    __syncthreads();
    s = rs[0] + rs[1] + rs[2] + rs[3];
    q = rq[0] + rq[1] + rq[2] + rq[3];
    float mean = s * (1.0f / 4608.0f);
    float var = q * (1.0f / 4608.0f) - mean * mean;
    float sc = rsqrtf(var + 1e-5f) * gamma[c];
    float sh = beta[c] - mean * sc;
#pragma unroll
    for (int i = 0; i < 18; i++) {
        int j = i * 256 + t;
        int b = j / NN, n = j % NN;
        out[(size_t)(b * CC + c) * NN + n] = vals[i] * sc + sh;
    }
}

// ---------------------------------------------------------------------------
extern "C" void kernel_launch(void* const* d_in, const int* in_sizes, int n_in,
                              void* d_out, int out_size, void* d_ws, size_t ws_size,
                              hipStream_t stream) {
    const float* x     = (const float*)d_in[0];
    const float* wqkv  = (const float*)d_in[1];
    const float* temp  = (const float*)d_in[2];
    const float* wout  = (const float*)d_in[3];
    const float* gamma = (const float*)d_in[4];
    const float* beta  = (const float*)d_in[5];
    float* out = (float*)d_out;
    char* ws = (char*)d_ws;

    // Size the cooperative grid from the occupancy query (host-side, capture
    // safe) so hipLaunchCooperativeKernel's validation cannot reject it.
    static int coop_blocks_per_cu = -1;
    if (coop_blocks_per_cu < 0) {
        int nb = 0;
        hipError_t qe = hipOccupancyMaxActiveBlocksPerMultiprocessor(
            &nb, (const void*)mega, 256, 0);
        coop_blocks_per_cu = (qe == hipSuccess && nb > 0) ? nb : 0;
    }

    if (coop_blocks_per_cu > 0) {
        int gsz = coop_blocks_per_cu * 256;   // MI355X: 256 CUs
        if (gsz > 1152) gsz = 1152;           // max work units (stage D)
        void* args[] = {(void*)&x, (void*)&wqkv, (void*)&temp, (void*)&wout,
                        (void*)&gamma, (void*)&beta, (void*)&out, (void*)&ws};
        hipError_t e = hipLaunchCooperativeKernel((const void*)mega, dim3(gsz),
                                                  dim3(256), args, 0, stream);
        if (e == hipSuccess) return;
    }

    // Fallback: verified round-1 five-kernel pipeline.
    __bf16* xT  = (__bf16*)(ws + OFF_XT);
    __bf16* wqb = (__bf16*)(ws + OFF_WQ);
    __bf16* wob = (__bf16*)(ws + OFF_WO);
    _Float16* Q  = (_Float16*)(ws + OFF_Q);
    _Float16* K  = (_Float16*)(ws + OFF_K);
    _Float16* VT = (_Float16*)(ws + OFF_VT);
    __bf16* AO  = (__bf16*)(ws + OFF_AO);

    k0_convert<<<640, 256, 0, stream>>>(x, wqkv, wout, xT, wqb, wob);
    k1_qkv<<<dim3(12, 36, 2), 256, 0, stream>>>(xT, wqb, Q, K, VT);
    k2_attn<<<dim3(36, 16), 512, 0, stream>>>(Q, K, VT, temp, AO);
    k3_proj<<<dim3(16, 36, 2), 256, 0, stream>>>(AO, wob, out);
    k4_bn<<<512, 256, 0, stream>>>(out, gamma, beta);
}

// Round 4
// 143.841 us; speedup vs baseline: 2.6869x; 2.6869x over previous
//
#include <hip/hip_runtime.h>

// Problem constants
#define NB 2
#define CC 512
#define NN 2304
#define NH 8
#define DD 16
#define TT 128          // NH*DD
#define O3 384          // 3*TT

typedef __attribute__((ext_vector_type(4))) float f32x4;
typedef __attribute__((ext_vector_type(8))) __bf16 bf16x8;
typedef __attribute__((ext_vector_type(4))) __bf16 bf16x4;
typedef __attribute__((ext_vector_type(4))) _Float16 f16x4;

// workspace layout (bytes) — xT/wqb/wob deleted (R4: conversions folded into
// consumers, k0 removed entirely to cut one dispatch + the xT round trip).
#define OFF_Q  0u               // 2*8*2304*16*2 = 1,179,648
#define OFF_K  1179648u
#define OFF_VT 2359296u
#define OFF_AO 3538944u         // 2*2304*128*2 = 1,179,648 -> 4,718,592

// ---------------------------------------------------------------------------
// Kernel 1: QKV GEMM  qkvT[n,o] = sum_c x[c,n] * W[o,c]  (per batch), reading
// x and w_qkv fp32 DIRECTLY (cvt->bf16 in-register; identical fragment values
// to the old k0+k1 path). Fused per-head L2 norm of q,k.
// A-frag: 8 strided dword loads (each coalesces to 4x64B segments, L2/L3-hot).
// Outputs: Q,K: [bh][n][16] f16 ; VT: [bh][16][n] f16
// ---------------------------------------------------------------------------
__global__ __launch_bounds__(256) void k1_qkv(
    const float* __restrict__ x, const float* __restrict__ wqkv,
    _Float16* __restrict__ Q, _Float16* __restrict__ K, _Float16* __restrict__ VT)
{
    int ob = blockIdx.x, nt = blockIdx.y, b = blockIdx.z;
    int lane = threadIdx.x & 63, wave = threadIdx.x >> 6;
    int quad = lane >> 4, col = lane & 15;
    int n0 = nt * 64 + wave * 16;
    int o0 = ob * 32;

    f32x4 acc0 = {0.f, 0.f, 0.f, 0.f};
    f32x4 acc1 = {0.f, 0.f, 0.f, 0.f};

    // A: x[b][c][n] with c = quad*8 + ks*32 + j, n = n0+col
    const float* ax  = x + (size_t)b * CC * NN + (size_t)(quad * 8) * NN + n0 + col;
    // B: w_qkv[o][c] rows o0+col (tile0) / o0+16+col (tile1), c chunk quad*8+ks*32
    const float* w0p = wqkv + (size_t)(o0 + col) * CC + quad * 8;
    const float* w1p = w0p + 16 * CC;

    float ca[8];
#pragma unroll
    for (int j = 0; j < 8; j++) ca[j] = ax[(size_t)j * NN];
    f32x4 cw0a = *(const f32x4*)(w0p);
    f32x4 cw0b = *(const f32x4*)(w0p + 4);
    f32x4 cw1a = *(const f32x4*)(w1p);
    f32x4 cw1b = *(const f32x4*)(w1p + 4);

#pragma unroll
    for (int ks = 0; ks < 16; ks++) {
        float na[8];
        f32x4 nw0a, nw0b, nw1a, nw1b;
        if (ks < 15) {
            const float* axn = ax + (size_t)(ks + 1) * 32 * NN;
#pragma unroll
            for (int j = 0; j < 8; j++) na[j] = axn[(size_t)j * NN];
            nw0a = *(const f32x4*)(w0p + (ks + 1) * 32);
            nw0b = *(const f32x4*)(w0p + (ks + 1) * 32 + 4);
            nw1a = *(const f32x4*)(w1p + (ks + 1) * 32);
            nw1b = *(const f32x4*)(w1p + (ks + 1) * 32 + 4);
        }
        bf16x8 af, wf0, wf1;
#pragma unroll
        for (int j = 0; j < 8; j++) af[j] = (__bf16)ca[j];
#pragma unroll
        for (int j = 0; j < 4; j++) {
            wf0[j]     = (__bf16)cw0a[j];
            wf0[j + 4] = (__bf16)cw0b[j];
            wf1[j]     = (__bf16)cw1a[j];
            wf1[j + 4] = (__bf16)cw1b[j];
        }
        acc0 = __builtin_amdgcn_mfma_f32_16x16x32_bf16(af, wf0, acc0, 0, 0, 0);
        acc1 = __builtin_amdgcn_mfma_f32_16x16x32_bf16(af, wf1, acc1, 0, 0, 0);
#pragma unroll
        for (int j = 0; j < 8; j++) ca[j] = na[j];
        cw0a = nw0a; cw0b = nw0b; cw1a = nw1a; cw1b = nw1b;
    }

#pragma unroll
    for (int s = 0; s < 2; s++) {
        int oc = o0 + s * 16 + col;
        int d = oc & 15, h = (oc >> 4) & 7, kind = oc >> 7;  // 0=q 1=k 2=v
        f32x4 v = (s == 0) ? acc0 : acc1;
        if (kind < 2) {
            float ss0 = v[0] * v[0], ss1 = v[1] * v[1], ss2 = v[2] * v[2], ss3 = v[3] * v[3];
#pragma unroll
            for (int m = 1; m < 16; m <<= 1) {
                ss0 += __shfl_xor(ss0, m);
                ss1 += __shfl_xor(ss1, m);
                ss2 += __shfl_xor(ss2, m);
                ss3 += __shfl_xor(ss3, m);
            }
            v[0] *= 1.0f / fmaxf(sqrtf(ss0), 1e-12f);
            v[1] *= 1.0f / fmaxf(sqrtf(ss1), 1e-12f);
            v[2] *= 1.0f / fmaxf(sqrtf(ss2), 1e-12f);
            v[3] *= 1.0f / fmaxf(sqrtf(ss3), 1e-12f);
            _Float16* dst = (kind == 0 ? Q : K) + (size_t)(b * NH + h) * NN * DD;
#pragma unroll
            for (int r = 0; r < 4; r++) {
                int n = n0 + quad * 4 + r;
                dst[(size_t)n * DD + d] = (_Float16)v[r];
            }
        } else {
            f16x4 pk;
#pragma unroll
            for (int r = 0; r < 4; r++) pk[r] = (_Float16)v[r];
            int n = n0 + quad * 4;
            *(f16x4*)(VT + (size_t)((b * NH + h) * DD + d) * NN + n) = pk;
        }
    }
}

// ---------------------------------------------------------------------------
// Kernel 2: attention — transpose-free flash via K=16 MFMAs with 4x register
// Q-blocking (64 q-rows per wave). Split-K inside the block: 8 waves x 288
// keys; partials combined through LDS; AO written directly. (Verified R1.)
//   S^T = mfma(A=K-frag, B=Q-frag): lane(quad,col) = S^T[key=quad*4+r][q=col]
//   exp2 in place -> same regs are the B-operand for O^T += mfma(A=V^T, B=P).
// Output: AO[b][n][t=h*16+d] bf16.
// ---------------------------------------------------------------------------
__global__ __launch_bounds__(512) void k2_attn(
    const _Float16* __restrict__ Q, const _Float16* __restrict__ K,
    const _Float16* __restrict__ VT, const float* __restrict__ temp,
    __bf16* __restrict__ AO)
{
    __shared__ float Osh[8][16][64];   // [wave][d][q]
    __shared__ float Lsh[8][64];       // [wave][q]

    int qt = blockIdx.x, bh = blockIdx.y;
    int lane = threadIdx.x & 63, wave = threadIdx.x >> 6;
    int quad = lane >> 4, col = lane & 15;
    int kbase = wave * 288;               // 8 waves x 288 keys = full 2304
    int qbase = qt * 64;

    const _Float16* Qb = Q + (size_t)bh * NN * DD;
    float tl2 = temp[bh & 7] * 1.4426950408889634f;   // exp(x)=2^(x*log2e)

    f16x4 qf0 = *(const f16x4*)(Qb + (size_t)(qbase +  0 + col) * DD + quad * 4);
    f16x4 qf1 = *(const f16x4*)(Qb + (size_t)(qbase + 16 + col) * DD + quad * 4);
    f16x4 qf2 = *(const f16x4*)(Qb + (size_t)(qbase + 32 + col) * DD + quad * 4);
    f16x4 qf3 = *(const f16x4*)(Qb + (size_t)(qbase + 48 + col) * DD + quad * 4);

    f32x4 oa0 = {0.f,0.f,0.f,0.f}, oa1 = {0.f,0.f,0.f,0.f};
    f32x4 oa2 = {0.f,0.f,0.f,0.f}, oa3 = {0.f,0.f,0.f,0.f};
    float la0 = 0.f, la1 = 0.f, la2 = 0.f, la3 = 0.f;
    const f32x4 zc = {0.f,0.f,0.f,0.f};

    const _Float16* kp = K + (size_t)bh * NN * DD + (size_t)(kbase + col) * DD + quad * 4;
    const _Float16* vp = VT + (size_t)bh * DD * NN + (size_t)col * NN + kbase + quad * 4;

    f16x4 kfa = *(const f16x4*)(kp);
    f16x4 kfb = *(const f16x4*)(kp + 16 * DD);
    f16x4 vfa = *(const f16x4*)(vp);
    f16x4 vfb = *(const f16x4*)(vp + 16);

#define K2_CHUNK(KF, VF)                                                        \
    {                                                                           \
        f32x4 s0 = __builtin_amdgcn_mfma_f32_16x16x16f16(KF, qf0, zc, 0, 0, 0); \
        f32x4 s1 = __builtin_amdgcn_mfma_f32_16x16x16f16(KF, qf1, zc, 0, 0, 0); \
        f32x4 s2 = __builtin_amdgcn_mfma_f32_16x16x16f16(KF, qf2, zc, 0, 0, 0); \
        f32x4 s3 = __builtin_amdgcn_mfma_f32_16x16x16f16(KF, qf3, zc, 0, 0, 0); \
        f16x4 p0, p1, p2, p3;                                                   \
        _Pragma("unroll")                                                       \
        for (int r = 0; r < 4; ++r) {                                           \
            float e0 = __builtin_amdgcn_exp2f(tl2 * s0[r]);                     \
            float e1 = __builtin_amdgcn_exp2f(tl2 * s1[r]);                     \
            float e2 = __builtin_amdgcn_exp2f(tl2 * s2[r]);                     \
            float e3 = __builtin_amdgcn_exp2f(tl2 * s3[r]);                     \
            p0[r] = (_Float16)e0; la0 += e0;                                    \
            p1[r] = (_Float16)e1; la1 += e1;                                    \
            p2[r] = (_Float16)e2; la2 += e2;                                    \
            p3[r] = (_Float16)e3; la3 += e3;                                    \
        }                                                                       \
        oa0 = __builtin_amdgcn_mfma_f32_16x16x16f16(VF, p0, oa0, 0, 0, 0);      \
        oa1 = __builtin_amdgcn_mfma_f32_16x16x16f16(VF, p1, oa1, 0, 0, 0);      \
        oa2 = __builtin_amdgcn_mfma_f32_16x16x16f16(VF, p2, oa2, 0, 0, 0);      \
        oa3 = __builtin_amdgcn_mfma_f32_16x16x16f16(VF, p3, oa3, 0, 0, 0);      \
    }

    for (int g = 0; g < 9; ++g) {        // 9 groups x 32 keys = 288
        f16x4 kna, knb, vna, vnb;
        if (g < 8) {
            kna = *(const f16x4*)(kp + 32 * DD);
            knb = *(const f16x4*)(kp + 48 * DD);
            vna = *(const f16x4*)(vp + 32);
            vnb = *(const f16x4*)(vp + 48);
        }
        K2_CHUNK(kfa, vfa)
        K2_CHUNK(kfb, vfb)
        kfa = kna; kfb = knb; vfa = vna; vfb = vnb;
        kp += 32 * DD; vp += 32;
    }
#undef K2_CHUNK

    la0 += __shfl_xor(la0, 16); la0 += __shfl_xor(la0, 32);
    la1 += __shfl_xor(la1, 16); la1 += __shfl_xor(la1, 32);
    la2 += __shfl_xor(la2, 16); la2 += __shfl_xor(la2, 32);
    la3 += __shfl_xor(la3, 16); la3 += __shfl_xor(la3, 32);

#pragma unroll
    for (int r = 0; r < 4; ++r) {
        Osh[wave][quad * 4 + r][ 0 + col] = oa0[r];
        Osh[wave][quad * 4 + r][16 + col] = oa1[r];
        Osh[wave][quad * 4 + r][32 + col] = oa2[r];
        Osh[wave][quad * 4 + r][48 + col] = oa3[r];
    }
    float lv = (quad == 0) ? la0 : (quad == 1) ? la1 : (quad == 2) ? la2 : la3;
    Lsh[wave][quad * 16 + col] = lv;
    __syncthreads();

    int t = threadIdx.x;
    int q = t & 63, dg = t >> 6;          // dg in 0..7 -> d = dg*2, dg*2+1
    float l = 0.f;
#pragma unroll
    for (int w = 0; w < 8; ++w) l += Lsh[w][q];
    float inv = 1.0f / l;
    float o0 = 0.f, o1 = 0.f;
#pragma unroll
    for (int w = 0; w < 8; ++w) {
        o0 += Osh[w][dg * 2 + 0][q];
        o1 += Osh[w][dg * 2 + 1][q];
    }
    int b = bh >> 3, h = bh & 7;
    __bf16* dst = AO + (size_t)(b * NN + qbase + q) * TT + h * DD + dg * 2;
    dst[0] = (__bf16)(o0 * inv);
    dst[1] = (__bf16)(o1 * inv);
}

// ---------------------------------------------------------------------------
// Kernel 3: projection  out[b,c,n] = sum_t w_out[c,t] * AO[b,n,t]  (pre-BN fp32
// straight into d_out). w_out read fp32 directly, cvt in-register.
// ---------------------------------------------------------------------------
__global__ __launch_bounds__(256) void k3_proj(
    const __bf16* __restrict__ AO, const float* __restrict__ wout,
    float* __restrict__ out)
{
    int cb = blockIdx.x, nt = blockIdx.y, b = blockIdx.z;
    int lane = threadIdx.x & 63, wave = threadIdx.x >> 6;
    int quad = lane >> 4, col = lane & 15;
    int n0 = nt * 64 + wave * 16, c0 = cb * 32;

    f32x4 acc0 = {0.f, 0.f, 0.f, 0.f};
    f32x4 acc1 = {0.f, 0.f, 0.f, 0.f};

    const __bf16* ab  = AO + (size_t)(b * NN + n0 + col) * TT + quad * 8;
    const float*  wb0 = wout + (size_t)(c0 + col) * TT + quad * 8;
    const float*  wb1 = wb0 + 16 * TT;
#pragma unroll
    for (int ks = 0; ks < 4; ks++) {
        bf16x8 a = *(const bf16x8*)(ab + ks * 32);
        f32x4 wA = *(const f32x4*)(wb0 + ks * 32);
        f32x4 wB = *(const f32x4*)(wb0 + ks * 32 + 4);
        f32x4 wC = *(const f32x4*)(wb1 + ks * 32);
        f32x4 wD = *(const f32x4*)(wb1 + ks * 32 + 4);
        bf16x8 w0, w1;
#pragma unroll
        for (int j = 0; j < 4; j++) {
            w0[j]     = (__bf16)wA[j];
            w0[j + 4] = (__bf16)wB[j];
            w1[j]     = (__bf16)wC[j];
            w1[j + 4] = (__bf16)wD[j];
        }
        acc0 = __builtin_amdgcn_mfma_f32_16x16x32_bf16(a, w0, acc0, 0, 0, 0);
        acc1 = __builtin_amdgcn_mfma_f32_16x16x32_bf16(a, w1, acc1, 0, 0, 0);
    }
#pragma unroll
    for (int s = 0; s < 2; s++) {
        int c = c0 + s * 16 + col;
        float* dst = out + (size_t)(b * CC + c) * NN + n0 + quad * 4;
        *(f32x4*)dst = (s == 0) ? acc0 : acc1;
    }
}

// ---------------------------------------------------------------------------
// Kernel 4: training-mode BatchNorm, in place on d_out. One block per channel.
// ---------------------------------------------------------------------------
__global__ __launch_bounds__(256) void k4_bn(
    float* __restrict__ out, const float* __restrict__ gamma,
    const float* __restrict__ beta)
{
    int c = blockIdx.x;
    int t = threadIdx.x;
    float vals[18];
    float s = 0.f, q = 0.f;
#pragma unroll
    for (int i = 0; i < 18; i++) {
        int j = i * 256 + t;          // 0..4607 over (b,n)
        int b = j / NN, n = j % NN;
        float v = out[(size_t)(b * CC + c) * NN + n];
        vals[i] = v; s += v; q += v * v;
    }
#pragma unroll
    for (int m = 1; m < 64; m <<= 1) { s += __shfl_xor(s, m); q += __shfl_xor(q, m); }
    __shared__ float rs[4], rq[4];
    int lane = t & 63, wave = t >> 6;
    if (lane == 0) { rs[wave] = s; rq[wave] = q; }
    __syncthreads();
    s = rs[0] + rs[1] + rs[2] + rs[3];
    q = rq[0] + rq[1] + rq[2] + rq[3];
    float mean = s * (1.0f / 4608.0f);
    float var = q * (1.0f / 4608.0f) - mean * mean;
    float sc = rsqrtf(var + 1e-5f) * gamma[c];
    float sh = beta[c] - mean * sc;
#pragma unroll
    for (int i = 0; i < 18; i++) {
        int j = i * 256 + t;
        int b = j / NN, n = j % NN;
        out[(size_t)(b * CC + c) * NN + n] = vals[i] * sc + sh;
    }
}

// ---------------------------------------------------------------------------
extern "C" void kernel_launch(void* const* d_in, const int* in_sizes, int n_in,
                              void* d_out, int out_size, void* d_ws, size_t ws_size,
                              hipStream_t stream) {
    const float* x     = (const float*)d_in[0];
    const float* wqkv  = (const float*)d_in[1];
    const float* temp  = (const float*)d_in[2];
    const float* wout  = (const float*)d_in[3];
    const float* gamma = (const float*)d_in[4];
    const float* beta  = (const float*)d_in[5];
    float* out = (float*)d_out;
    char* ws = (char*)d_ws;

    _Float16* Q  = (_Float16*)(ws + OFF_Q);
    _Float16* K  = (_Float16*)(ws + OFF_K);
    _Float16* VT = (_Float16*)(ws + OFF_VT);
    __bf16*   AO = (__bf16*)(ws + OFF_AO);

    k1_qkv<<<dim3(12, 36, 2), 256, 0, stream>>>(x, wqkv, Q, K, VT);
    k2_attn<<<dim3(36, 16), 512, 0, stream>>>(Q, K, VT, temp, AO);
    k3_proj<<<dim3(16, 36, 2), 256, 0, stream>>>(AO, wout, out);
    k4_bn<<<512, 256, 0, stream>>>(out, gamma, beta);
}

// Round 6
// 134.138 us; speedup vs baseline: 2.8813x; 1.0723x over previous
//
#include <hip/hip_runtime.h>

// Problem constants
#define NB 2
#define CC 512
#define NN 2304
#define NH 8
#define DD 16
#define TT 128          // NH*DD
#define O3 384          // 3*TT

typedef __attribute__((ext_vector_type(4))) float f32x4;
typedef __attribute__((ext_vector_type(8))) __bf16 bf16x8;
typedef __attribute__((ext_vector_type(4))) __bf16 bf16x4;
typedef __attribute__((ext_vector_type(4))) _Float16 f16x4;
typedef __attribute__((ext_vector_type(2))) __fp16 hf16x2;   // cvt_pkrtz return type

union hf2pair {                       // bit-reinterpret 2x(__fp16 x2) -> f16x4
    hf16x2 h[2];
    f16x4  v;
};

// workspace layout (bytes)
#define OFF_XT 0u               // 2*2304*512*2 = 4,718,592
#define OFF_WQ 4718592u         // 384*512*2    =   393,216
#define OFF_WO 5111808u         // 512*128*2    =   131,072
#define OFF_Q  5242880u         // 2*8*2304*16*2 = 1,179,648
#define OFF_K  6422528u
#define OFF_VT 7602176u
#define OFF_AO 8781824u         // 2*2304*128*2 = 1,179,648 -> 9,961,472

// ---------------------------------------------------------------------------
// Kernel 0: convert x [b,c,n] fp32 -> xT [b,n,c] bf16 (LDS tile transpose),
//           plus straight fp32->bf16 conversion of w_qkv and w_out.
// ---------------------------------------------------------------------------
__global__ __launch_bounds__(256) void k0_convert(
    const float* __restrict__ x, const float* __restrict__ wqkv,
    const float* __restrict__ wout,
    __bf16* __restrict__ xT, __bf16* __restrict__ wqb, __bf16* __restrict__ wob)
{
    int bid = blockIdx.x;
    int t = threadIdx.x;
    if (bid < 576) {
        __shared__ float tile[64][65];
        int b = bid / 288, rem = bid % 288;
        int nt = rem / 8, cb = rem % 8;
        int n0 = nt * 64, c0 = cb * 64;
        int tc = t >> 6, tn = t & 63;
#pragma unroll
        for (int i = 0; i < 16; i++) {
            int cl = i * 4 + tc;
            tile[cl][tn] = x[(size_t)(b * CC + c0 + cl) * NN + n0 + tn];
        }
        __syncthreads();
#pragma unroll
        for (int i = 0; i < 16; i++) {
            int nl = i * 4 + tc;
            xT[(size_t)(b * NN + n0 + nl) * CC + c0 + tn] = (__bf16)tile[tn][nl];
        }
    } else {
        int wid = bid - 576;
        int base = wid * 256 + t;
#pragma unroll
        for (int i = 0; i < 16; i++) {
            int j = base + i * 16384;           // covers 262144 = 384*512 + 512*128
            if (j < O3 * CC) wqb[j] = (__bf16)wqkv[j];
            else             wob[j - O3 * CC] = (__bf16)wout[j - O3 * CC];
        }
    }
}

// ---------------------------------------------------------------------------
// Kernel 1: QKV GEMM  qkvT[n,o] = sum_c xT[n,c] * W[o,c]  (per batch),
//           fused per-head L2 norm of q,k.
// R5: ob 12->6 (64 output channels / block, 4 acc tiles/wave): halves the
// L2 re-read of xT and W, doubles MFMA per A-load.
// Outputs: Q,K: [bh][n][16] f16 ;  VT: [bh][16][n] f16
// ---------------------------------------------------------------------------
__global__ __launch_bounds__(256) void k1_qkv(
    const __bf16* __restrict__ xT, const __bf16* __restrict__ wqb,
    _Float16* __restrict__ Q, _Float16* __restrict__ K, _Float16* __restrict__ VT)
{
    int ob = blockIdx.x, nt = blockIdx.y, b = blockIdx.z;
    int lane = threadIdx.x & 63, wave = threadIdx.x >> 6;
    int quad = lane >> 4, col = lane & 15;
    int n0 = nt * 64 + wave * 16;
    int o0 = ob * 64;

    f32x4 acc0 = {0.f,0.f,0.f,0.f}, acc1 = {0.f,0.f,0.f,0.f};
    f32x4 acc2 = {0.f,0.f,0.f,0.f}, acc3 = {0.f,0.f,0.f,0.f};

    const __bf16* arow  = xT + (size_t)(b * NN + n0 + col) * CC + quad * 8;
    const __bf16* brow0 = wqb + (size_t)(o0 + col) * CC + quad * 8;
    const __bf16* brow1 = brow0 + 16 * CC;
    const __bf16* brow2 = brow0 + 32 * CC;
    const __bf16* brow3 = brow0 + 48 * CC;

    bf16x8 a  = *(const bf16x8*)(arow);
    bf16x8 w0 = *(const bf16x8*)(brow0);
    bf16x8 w1 = *(const bf16x8*)(brow1);
    bf16x8 w2 = *(const bf16x8*)(brow2);
    bf16x8 w3 = *(const bf16x8*)(brow3);
#pragma unroll
    for (int ks = 0; ks < 16; ks++) {
        bf16x8 an, wn0, wn1, wn2, wn3;
        if (ks < 15) {
            an  = *(const bf16x8*)(arow + (ks + 1) * 32);
            wn0 = *(const bf16x8*)(brow0 + (ks + 1) * 32);
            wn1 = *(const bf16x8*)(brow1 + (ks + 1) * 32);
            wn2 = *(const bf16x8*)(brow2 + (ks + 1) * 32);
            wn3 = *(const bf16x8*)(brow3 + (ks + 1) * 32);
        }
        acc0 = __builtin_amdgcn_mfma_f32_16x16x32_bf16(a, w0, acc0, 0, 0, 0);
        acc1 = __builtin_amdgcn_mfma_f32_16x16x32_bf16(a, w1, acc1, 0, 0, 0);
        acc2 = __builtin_amdgcn_mfma_f32_16x16x32_bf16(a, w2, acc2, 0, 0, 0);
        acc3 = __builtin_amdgcn_mfma_f32_16x16x32_bf16(a, w3, acc3, 0, 0, 0);
        a = an; w0 = wn0; w1 = wn1; w2 = wn2; w3 = wn3;
    }

#pragma unroll
    for (int s = 0; s < 4; s++) {
        int oc = o0 + s * 16 + col;
        int d = oc & 15, h = (oc >> 4) & 7, kind = oc >> 7;  // 0=q 1=k 2=v
        f32x4 v = (s == 0) ? acc0 : (s == 1) ? acc1 : (s == 2) ? acc2 : acc3;
        if (kind < 2) {
            float ss0 = v[0] * v[0], ss1 = v[1] * v[1], ss2 = v[2] * v[2], ss3 = v[3] * v[3];
#pragma unroll
            for (int m = 1; m < 16; m <<= 1) {
                ss0 += __shfl_xor(ss0, m);
                ss1 += __shfl_xor(ss1, m);
                ss2 += __shfl_xor(ss2, m);
                ss3 += __shfl_xor(ss3, m);
            }
            v[0] *= 1.0f / fmaxf(sqrtf(ss0), 1e-12f);
            v[1] *= 1.0f / fmaxf(sqrtf(ss1), 1e-12f);
            v[2] *= 1.0f / fmaxf(sqrtf(ss2), 1e-12f);
            v[3] *= 1.0f / fmaxf(sqrtf(ss3), 1e-12f);
            _Float16* dst = (kind == 0 ? Q : K) + (size_t)(b * NH + h) * NN * DD;
#pragma unroll
            for (int r = 0; r < 4; r++) {
                int n = n0 + quad * 4 + r;
                dst[(size_t)n * DD + d] = (_Float16)v[r];
            }
        } else {
            f16x4 pk;
#pragma unroll
            for (int r = 0; r < 4; r++) pk[r] = (_Float16)v[r];
            int n = n0 + quad * 4;
            *(f16x4*)(VT + (size_t)((b * NH + h) * DD + d) * NN + n) = pk;
        }
    }
}

// ---------------------------------------------------------------------------
// Kernel 2: attention — transpose-free flash, 8 waves x 288 keys, LDS combine.
// R5 VALU-diet: (a) temperature*log2e folded into the Q fragments (f16 mul
// once per block) so the exp2 arg is the raw MFMA output; (b) packed
// v_cvt_pkrtz for P f32->f16 (halves cvt count, union-reinterpreted to
// f16x4 — cvt_pkrtz returns __fp16x2, not _Float16x2); (c) per-q row-sum l
// via a ones-A-fragment MFMA per P frag (row 0 = l partial; replaces 16
// scalar fma/chunk + the final cross-quad shuffle reduce).
// Output: AO[b][n][t=h*16+d] bf16.
// ---------------------------------------------------------------------------
__global__ __launch_bounds__(512) void k2_attn(
    const _Float16* __restrict__ Q, const _Float16* __restrict__ K,
    const _Float16* __restrict__ VT, const float* __restrict__ temp,
    __bf16* __restrict__ AO)
{
    __shared__ float Osh[8][16][64];   // [wave][d][q]
    __shared__ float Lsh[8][64];       // [wave][q]

    int qt = blockIdx.x, bh = blockIdx.y;
    int lane = threadIdx.x & 63, wave = threadIdx.x >> 6;
    int quad = lane >> 4, col = lane & 15;
    int kbase = wave * 288;               // 8 waves x 288 keys = full 2304
    int qbase = qt * 64;

    const _Float16* Qb = Q + (size_t)bh * NN * DD;
    float tl2 = temp[bh & 7] * 1.4426950408889634f;   // exp(x)=2^(x*log2e)
    _Float16 tl2h = (_Float16)tl2;

    f16x4 qf0 = *(const f16x4*)(Qb + (size_t)(qbase +  0 + col) * DD + quad * 4);
    f16x4 qf1 = *(const f16x4*)(Qb + (size_t)(qbase + 16 + col) * DD + quad * 4);
    f16x4 qf2 = *(const f16x4*)(Qb + (size_t)(qbase + 32 + col) * DD + quad * 4);
    f16x4 qf3 = *(const f16x4*)(Qb + (size_t)(qbase + 48 + col) * DD + quad * 4);
#pragma unroll
    for (int j = 0; j < 4; j++) {      // fold temperature*log2e into Q
        qf0[j] *= tl2h; qf1[j] *= tl2h; qf2[j] *= tl2h; qf3[j] *= tl2h;
    }
    const f16x4 onesf = {(_Float16)1.f, (_Float16)1.f, (_Float16)1.f, (_Float16)1.f};

    f32x4 oa0 = {0.f,0.f,0.f,0.f}, oa1 = {0.f,0.f,0.f,0.f};
    f32x4 oa2 = {0.f,0.f,0.f,0.f}, oa3 = {0.f,0.f,0.f,0.f};
    f32x4 lc0 = {0.f,0.f,0.f,0.f}, lc1 = {0.f,0.f,0.f,0.f};
    f32x4 lc2 = {0.f,0.f,0.f,0.f}, lc3 = {0.f,0.f,0.f,0.f};
    const f32x4 zc = {0.f,0.f,0.f,0.f};

    const _Float16* kp = K + (size_t)bh * NN * DD + (size_t)(kbase + col) * DD + quad * 4;
    const _Float16* vp = VT + (size_t)bh * DD * NN + (size_t)col * NN + kbase + quad * 4;

    f16x4 kfa = *(const f16x4*)(kp);
    f16x4 kfb = *(const f16x4*)(kp + 16 * DD);
    f16x4 vfa = *(const f16x4*)(vp);
    f16x4 vfb = *(const f16x4*)(vp + 16);

#define K2_CHUNK(KF, VF)                                                        \
    {                                                                           \
        f32x4 s0 = __builtin_amdgcn_mfma_f32_16x16x16f16(KF, qf0, zc, 0, 0, 0); \
        f32x4 s1 = __builtin_amdgcn_mfma_f32_16x16x16f16(KF, qf1, zc, 0, 0, 0); \
        f32x4 s2 = __builtin_amdgcn_mfma_f32_16x16x16f16(KF, qf2, zc, 0, 0, 0); \
        f32x4 s3 = __builtin_amdgcn_mfma_f32_16x16x16f16(KF, qf3, zc, 0, 0, 0); \
        hf2pair u0, u1, u2, u3;                                                 \
        u0.h[0] = __builtin_amdgcn_cvt_pkrtz(__builtin_amdgcn_exp2f(s0[0]),     \
                                             __builtin_amdgcn_exp2f(s0[1]));    \
        u0.h[1] = __builtin_amdgcn_cvt_pkrtz(__builtin_amdgcn_exp2f(s0[2]),     \
                                             __builtin_amdgcn_exp2f(s0[3]));    \
        u1.h[0] = __builtin_amdgcn_cvt_pkrtz(__builtin_amdgcn_exp2f(s1[0]),     \
                                             __builtin_amdgcn_exp2f(s1[1]));    \
        u1.h[1] = __builtin_amdgcn_cvt_pkrtz(__builtin_amdgcn_exp2f(s1[2]),     \
                                             __builtin_amdgcn_exp2f(s1[3]));    \
        u2.h[0] = __builtin_amdgcn_cvt_pkrtz(__builtin_amdgcn_exp2f(s2[0]),     \
                                             __builtin_amdgcn_exp2f(s2[1]));    \
        u2.h[1] = __builtin_amdgcn_cvt_pkrtz(__builtin_amdgcn_exp2f(s2[2]),     \
                                             __builtin_amdgcn_exp2f(s2[3]));    \
        u3.h[0] = __builtin_amdgcn_cvt_pkrtz(__builtin_amdgcn_exp2f(s3[0]),     \
                                             __builtin_amdgcn_exp2f(s3[1]));    \
        u3.h[1] = __builtin_amdgcn_cvt_pkrtz(__builtin_amdgcn_exp2f(s3[2]),     \
                                             __builtin_amdgcn_exp2f(s3[3]));    \
        f16x4 p0 = u0.v, p1 = u1.v, p2 = u2.v, p3 = u3.v;                       \
        lc0 = __builtin_amdgcn_mfma_f32_16x16x16f16(onesf, p0, lc0, 0, 0, 0);   \
        lc1 = __builtin_amdgcn_mfma_f32_16x16x16f16(onesf, p1, lc1, 0, 0, 0);   \
        lc2 = __builtin_amdgcn_mfma_f32_16x16x16f16(onesf, p2, lc2, 0, 0, 0);   \
        lc3 = __builtin_amdgcn_mfma_f32_16x16x16f16(onesf, p3, lc3, 0, 0, 0);   \
        oa0 = __builtin_amdgcn_mfma_f32_16x16x16f16(VF, p0, oa0, 0, 0, 0);      \
        oa1 = __builtin_amdgcn_mfma_f32_16x16x16f16(VF, p1, oa1, 0, 0, 0);      \
        oa2 = __builtin_amdgcn_mfma_f32_16x16x16f16(VF, p2, oa2, 0, 0, 0);      \
        oa3 = __builtin_amdgcn_mfma_f32_16x16x16f16(VF, p3, oa3, 0, 0, 0);      \
    }

    for (int g = 0; g < 9; ++g) {        // 9 groups x 32 keys = 288
        f16x4 kna, knb, vna, vnb;
        if (g < 8) {
            kna = *(const f16x4*)(kp + 32 * DD);
            knb = *(const f16x4*)(kp + 48 * DD);
            vna = *(const f16x4*)(vp + 32);
            vnb = *(const f16x4*)(vp + 48);
        }
        K2_CHUNK(kfa, vfa)
        K2_CHUNK(kfb, vfb)
        kfa = kna; kfb = knb; vfa = vna; vfb = vnb;
        kp += 32 * DD; vp += 32;
    }
#undef K2_CHUNK

    // lc rows are all identical = l[q=col] partial over this wave's keys.
#pragma unroll
    for (int r = 0; r < 4; ++r) {
        Osh[wave][quad * 4 + r][ 0 + col] = oa0[r];
        Osh[wave][quad * 4 + r][16 + col] = oa1[r];
        Osh[wave][quad * 4 + r][32 + col] = oa2[r];
        Osh[wave][quad * 4 + r][48 + col] = oa3[r];
    }
    float lv = (quad == 0) ? lc0[0] : (quad == 1) ? lc1[0] : (quad == 2) ? lc2[0] : lc3[0];
    Lsh[wave][quad * 16 + col] = lv;
    __syncthreads();

    int t = threadIdx.x;
    int q = t & 63, dg = t >> 6;          // dg in 0..7 -> d = dg*2, dg*2+1
    float l = 0.f;
#pragma unroll
    for (int w = 0; w < 8; ++w) l += Lsh[w][q];
    float inv = 1.0f / l;
    float o0 = 0.f, o1 = 0.f;
#pragma unroll
    for (int w = 0; w < 8; ++w) {
        o0 += Osh[w][dg * 2 + 0][q];
        o1 += Osh[w][dg * 2 + 1][q];
    }
    int b = bh >> 3, h = bh & 7;
    __bf16* dst = AO + (size_t)(b * NN + qbase + q) * TT + h * DD + dg * 2;
    dst[0] = (__bf16)(o0 * inv);
    dst[1] = (__bf16)(o1 * inv);
}

// ---------------------------------------------------------------------------
// Kernel 3: projection  out[b,c,n] = sum_t w_out[c,t] * AO[b,n,t]  (pre-BN fp32
// straight into d_out). c-slab 32 per wave: grid (16,36,2)=1152 blocks.
// ---------------------------------------------------------------------------
__global__ __launch_bounds__(256) void k3_proj(
    const __bf16* __restrict__ AO, const __bf16* __restrict__ wob,
    float* __restrict__ out)
{
    int cb = blockIdx.x, nt = blockIdx.y, b = blockIdx.z;
    int lane = threadIdx.x & 63, wave = threadIdx.x >> 6;
    int quad = lane >> 4, col = lane & 15;
    int n0 = nt * 64 + wave * 16, c0 = cb * 32;

    f32x4 acc0 = {0.f, 0.f, 0.f, 0.f};
    f32x4 acc1 = {0.f, 0.f, 0.f, 0.f};

    const __bf16* ab = AO + (size_t)(b * NN + n0 + col) * TT + quad * 8;
    const __bf16* wb0 = wob + (size_t)(c0 + col) * TT + quad * 8;
    const __bf16* wb1 = wb0 + 16 * TT;
#pragma unroll
    for (int ks = 0; ks < 4; ks++) {
        bf16x8 a  = *(const bf16x8*)(ab + ks * 32);
        bf16x8 w0 = *(const bf16x8*)(wb0 + ks * 32);
        bf16x8 w1 = *(const bf16x8*)(wb1 + ks * 32);
        acc0 = __builtin_amdgcn_mfma_f32_16x16x32_bf16(a, w0, acc0, 0, 0, 0);
        acc1 = __builtin_amdgcn_mfma_f32_16x16x32_bf16(a, w1, acc1, 0, 0, 0);
    }
#pragma unroll
    for (int s = 0; s < 2; s++) {
        int c = c0 + s * 16 + col;
        float* dst = out + (size_t)(b * CC + c) * NN + n0 + quad * 4;
        *(f32x4*)dst = (s == 0) ? acc0 : acc1;
    }
}

// ---------------------------------------------------------------------------
// Kernel 4: training-mode BatchNorm, in place on d_out. One block per channel.
// ---------------------------------------------------------------------------
__global__ __launch_bounds__(256) void k4_bn(
    float* __restrict__ out, const float* __restrict__ gamma,
    const float* __restrict__ beta)
{
    int c = blockIdx.x;
    int t = threadIdx.x;
    float vals[18];
    float s = 0.f, q = 0.f;
#pragma unroll
    for (int i = 0; i < 18; i++) {
        int j = i * 256 + t;          // 0..4607 over (b,n)
        int b = j / NN, n = j % NN;
        float v = out[(size_t)(b * CC + c) * NN + n];
        vals[i] = v; s += v; q += v * v;
    }
#pragma unroll
    for (int m = 1; m < 64; m <<= 1) { s += __shfl_xor(s, m); q += __shfl_xor(q, m); }
    __shared__ float rs[4], rq[4];
    int lane = t & 63, wave = t >> 6;
    if (lane == 0) { rs[wave] = s; rq[wave] = q; }
    __syncthreads();
    s = rs[0] + rs[1] + rs[2] + rs[3];
    q = rq[0] + rq[1] + rq[2] + rq[3];
    float mean = s * (1.0f / 4608.0f);
    float var = q * (1.0f / 4608.0f) - mean * mean;
    float sc = rsqrtf(var + 1e-5f) * gamma[c];
    float sh = beta[c] - mean * sc;
#pragma unroll
    for (int i = 0; i < 18; i++) {
        int j = i * 256 + t;
        int b = j / NN, n = j % NN;
        out[(size_t)(b * CC + c) * NN + n] = vals[i] * sc + sh;
    }
}

// ---------------------------------------------------------------------------
extern "C" void kernel_launch(void* const* d_in, const int* in_sizes, int n_in,
                              void* d_out, int out_size, void* d_ws, size_t ws_size,
                              hipStream_t stream) {
    const float* x     = (const float*)d_in[0];
    const float* wqkv  = (const float*)d_in[1];
    const float* temp  = (const float*)d_in[2];
    const float* wout  = (const float*)d_in[3];
    const float* gamma = (const float*)d_in[4];
    const float* beta  = (const float*)d_in[5];
    float* out = (float*)d_out;
    char* ws = (char*)d_ws;

    __bf16* xT  = (__bf16*)(ws + OFF_XT);
    __bf16* wqb = (__bf16*)(ws + OFF_WQ);
    __bf16* wob = (__bf16*)(ws + OFF_WO);
    _Float16* Q  = (_Float16*)(ws + OFF_Q);
    _Float16* K  = (_Float16*)(ws + OFF_K);
    _Float16* VT = (_Float16*)(ws + OFF_VT);
    __bf16* AO  = (__bf16*)(ws + OFF_AO);

    k0_convert<<<640, 256, 0, stream>>>(x, wqkv, wout, xT, wqb, wob);
    k1_qkv<<<dim3(6, 36, 2), 256, 0, stream>>>(xT, wqb, Q, K, VT);
    k2_attn<<<dim3(36, 16), 512, 0, stream>>>(Q, K, VT, temp, AO);
    k3_proj<<<dim3(16, 36, 2), 256, 0, stream>>>(AO, wob, out);
    k4_bn<<<512, 256, 0, stream>>>(out, gamma, beta);
}